// Round 5
// baseline (324.195 us; speedup 1.0000x reference)
//
#include <hip/hip_runtime.h>
#include <cstdint>

typedef unsigned short u16;
typedef uint32_t u32;
typedef __bf16 bf16x8 __attribute__((ext_vector_type(8)));
typedef float f32x4 __attribute__((ext_vector_type(4)));

__device__ __forceinline__ u16 f2bf(float f) {
  unsigned u = __float_as_uint(f);
  u += 0x7fffu + ((u >> 16) & 1u);
  return (u16)(u >> 16);
}

__device__ __forceinline__ void async16(const void* g, void* l) {
  __builtin_amdgcn_global_load_lds(
      (const __attribute__((address_space(1))) uint32_t*)g,
      (__attribute__((address_space(3))) uint32_t*)l, 16, 0, 0);
}

// --- fused prep: x->bf16 | proj_w^T | out_w^T | mask bitpack (one dispatch) ---
__global__ __launch_bounds__(256) void k_prep(const float* __restrict__ x, u16* __restrict__ xb,
                                              const float* __restrict__ pw, u16* __restrict__ wt,
                                              const float* __restrict__ ow, u16* __restrict__ owt,
                                              const int* __restrict__ mask, u32* __restrict__ mbits) {
  const int bid = blockIdx.x;
  if (bid < 8192) {
    const int i = bid * 256 + threadIdx.x;
    const float4 v = ((const float4*)x)[i];
    ushort4 o;
    o.x = f2bf(v.x); o.y = f2bf(v.y); o.z = f2bf(v.z); o.w = f2bf(v.w);
    ((ushort4*)xb)[i] = o;
    return;
  }
  if (bid >= 12288) {
    const size_t w = (size_t)(bid - 12288) * 256 + threadIdx.x;
    const int* p = mask + w * 32;
    u32 bits = 0;
#pragma unroll
    for (int j = 0; j < 8; ++j) {
      const int4 v = ((const int4*)p)[j];
      bits |= (u32)(v.x & 1) << (j * 4 + 0);
      bits |= (u32)(v.y & 1) << (j * 4 + 1);
      bits |= (u32)(v.z & 1) << (j * 4 + 2);
      bits |= (u32)(v.w & 1) << (j * 4 + 3);
    }
    mbits[w] = bits;
    return;
  }
  __shared__ u16 tile[32][33];
  const int tx = threadIdx.x & 31, ty = threadIdx.x >> 5;
  const float* in;
  u16* outp;
  int lda, ldo, c0, r0;
  if (bid < 11264) {
    const int id = bid - 8192;  // proj_w [1024][3072] -> wt [3072][1024]
    c0 = (id % 96) * 32; r0 = (id / 96) * 32;
    in = pw; outp = wt; lda = 3072; ldo = 1024;
  } else {
    const int id = bid - 11264;  // out_w [1024][1024] -> owt
    c0 = (id % 32) * 32; r0 = (id / 32) * 32;
    in = ow; outp = owt; lda = 1024; ldo = 1024;
  }
#pragma unroll
  for (int i = 0; i < 4; ++i)
    tile[ty + i * 8][tx] = f2bf(in[(size_t)(r0 + ty + i * 8) * lda + c0 + tx]);
  __syncthreads();
#pragma unroll
  for (int i = 0; i < 4; ++i)
    outp[(size_t)(c0 + ty + i * 8) * ldo + r0 + tx] = tile[tx][ty + i * 8];
}

// =====================================================================
// 256x256-tile deep-pipelined core: 512 thr = 8 waves 2x4, BK=32,
// 4 LDS buffers. Per inter-barrier window (one K-tile):
//   READ(t+1)  -- 12 ds_read_b128 issued, NOT waited this window
//   STAGE(t+3) -- 4 global_load_lds
//   lgkmcnt(12) -- waits ONLY the previous window's 12 reads (CUR frags)
//   32 MFMA on CUR (reads of t+1 drain in LDS pipe underneath)
//   vmcnt(4) -- counted: lands tile t+2 (next window's READ target),
//               leaves t+3 in flight; sits AFTER MFMA so it's covered
//   s_barrier
// This fixes r2 (reads+MFMA serial: 2740cy/tile ~ 1241 MFMA + 1385 LDS)
// and r4 (vmcnt stall exposed before barrier with no compute cover).
// LDS layout: 128 lines x 128B; line l = rows {2l,2l+1}; group gg = go^(l&7),
// go=(row&1)*4+k16 -> 2-way max = free (0 conflicts measured r2).
// global_load_lds dest LINEAR; source carries the inverse permutation.
// MODE 0: +bias[col], cols<1024 *1/32, bf16 | MODE 1: mask+exp, bf16
// =====================================================================
template <int MODE>
__global__ __launch_bounds__(512, 2) void gemm256(
    const u16* __restrict__ A, long lda, long bsA,
    const u16* __restrict__ Bt, long ldb, long bsB,
    void* __restrict__ C, long ldc, long bsC,
    int M, int N, int K,
    const float* __restrict__ bias, const u32* __restrict__ mbits) {
  __shared__ u16 sm[4][2][8192];  // [buf][A|B][128 lines * 64 u16] = 128 KiB
  const int gx = gridDim.x, gxy = gridDim.x * gridDim.y;
  const int T = gxy * gridDim.z;
  int L = blockIdx.x + gx * blockIdx.y + gxy * blockIdx.z;
  L = (L & 7) * (T >> 3) + (L >> 3);  // XCD swizzle; T divisible by 8
  const int b = L / gxy, rr = L % gxy, bx = rr % gx, by = rr / gx;
  const int m0 = by * 256, n0 = bx * 256;
  const int tid = threadIdx.x;
  const int lane = tid & 63;
  const int w = tid >> 6;
  const int wr = w >> 2, wc = w & 3;  // 2 x 4 waves, wave tile 128x64

  // ---- staging: thread tid fills 16B slot tid (call 1) / tid+512 (call 2).
  const int sl = tid >> 3;
  const int sgo = (tid & 7) ^ (sl & 7);
  const int srow = 2 * sl + (sgo >> 2);
  const int skoff = (sgo & 3) * 8;
  const u16* pa = A + (size_t)b * bsA + (size_t)(m0 + srow) * lda + skoff;
  const u16* pb = Bt + (size_t)b * bsB + (size_t)(n0 + srow) * ldb + skoff;
  const size_t a128 = (size_t)128 * lda, b128 = (size_t)128 * ldb;

  // ---- fragment read bases (u16): row r, k16=q -> line r>>1,
  // g = ((r&1)*4 + q) ^ ((r>>1)&7), addr = line*64 + g*8.
  const int m_l = lane & 15, q = lane >> 4;
  const int l7 = m_l >> 1;
  const int g = (((m_l & 1) * 4) + q) ^ l7;
  const int aoff = wr * 4096 + l7 * 64 + g * 8;
  const int boff = wc * 2048 + l7 * 64 + g * 8;

  f32x4 acc[8][4] = {};
  bf16x8 a0[8], b0[4], a1[8], b1[4];

#define MFMA_(A_, B_, C_) __builtin_amdgcn_mfma_f32_16x16x32_bf16(A_, B_, C_, 0, 0, 0)
#define STAGE(tt)                                   \
  {                                                 \
    const int bi_ = (tt)&3;                         \
    const size_t ko_ = (size_t)(tt)*32;             \
    u16* da_ = &sm[bi_][0][0] + tid * 8;            \
    u16* db_ = &sm[bi_][1][0] + tid * 8;            \
    async16(pa + ko_, da_);                         \
    async16(pa + ko_ + a128, da_ + 4096);           \
    async16(pb + ko_, db_);                         \
    async16(pb + ko_ + b128, db_ + 4096);           \
  }
#define READ(NA, NB, tt)                                          \
  {                                                               \
    const u16* ab_ = &sm[(tt)&3][0][0] + aoff;                    \
    const u16* bb_ = &sm[(tt)&3][1][0] + boff;                    \
    _Pragma("unroll") for (int mt = 0; mt < 8; ++mt)              \
        NA[mt] = *(const bf16x8*)(ab_ + mt * 512);                \
    _Pragma("unroll") for (int nt = 0; nt < 4; ++nt)              \
        NB[nt] = *(const bf16x8*)(bb_ + nt * 512);                \
  }
// ITER(t): reads for t+1 issued ABOVE the MFMA cluster of t (same window);
// counted lgkm waits only the PREVIOUS reads; counted vmcnt after MFMA.
#define ITER(t, CA, CB, NA, NB)                              \
  {                                                          \
    if ((t) + 1 < NTL) { READ(NA, NB, (t) + 1) }             \
    if ((t) + 3 < NTL) STAGE((t) + 3)                        \
    if ((t) + 1 < NTL) {                                     \
      asm volatile("s_waitcnt lgkmcnt(12)" ::: "memory");    \
    } else {                                                 \
      asm volatile("s_waitcnt lgkmcnt(0)" ::: "memory");     \
    }                                                        \
    __builtin_amdgcn_sched_barrier(0);                       \
    __builtin_amdgcn_s_setprio(1);                           \
    _Pragma("unroll") for (int mt = 0; mt < 8; ++mt)         \
        _Pragma("unroll") for (int nt = 0; nt < 4; ++nt)     \
            acc[mt][nt] = MFMA_(CA[mt], CB[nt], acc[mt][nt]);\
    __builtin_amdgcn_s_setprio(0);                           \
    __builtin_amdgcn_sched_barrier(0);                       \
    if ((t) + 3 < NTL) {                                     \
      asm volatile("s_waitcnt vmcnt(4)" ::: "memory");       \
    } else if ((t) + 3 == NTL) {                             \
      asm volatile("s_waitcnt vmcnt(0)" ::: "memory");       \
    }                                                        \
    if ((t) + 1 < NTL) __builtin_amdgcn_s_barrier();         \
  }

  const int NTL = K >> 5;  // K-tiles of 32 (even for all our shapes)
  STAGE(0) STAGE(1) STAGE(2)
  asm volatile("s_waitcnt vmcnt(4)" ::: "memory");  // tiles 0,1 landed
  __builtin_amdgcn_s_barrier();
  READ(a0, b0, 0)

  for (int t = 0; t < NTL; t += 2) {
    ITER(t, a0, b0, a1, b1)
    ITER(t + 1, a1, b1, a0, b0)
  }
#undef ITER
#undef READ
#undef STAGE
#undef MFMA_

  if constexpr (MODE == 1) {
    __syncthreads();
    u32* smw = (u32*)&sm[0][0][0];
    const int rl = tid >> 1, wo = (tid & 1) * 4;
    const uint4 mv = *(const uint4*)(mbits + ((size_t)b * M + m0 + rl) * (N >> 5) + (n0 >> 5) + wo);
    smw[rl * 8 + wo] = mv.x;
    smw[rl * 8 + wo + 1] = mv.y;
    smw[rl * 8 + wo + 2] = mv.z;
    smw[rl * 8 + wo + 3] = mv.w;
    __syncthreads();
  }

#pragma unroll
  for (int mt = 0; mt < 8; ++mt) {
#pragma unroll
    for (int nt = 0; nt < 4; ++nt) {
      const int col = n0 + wc * 64 + nt * 16 + m_l;
      const int row0 = m0 + wr * 128 + mt * 16 + q * 4;
#pragma unroll
      for (int r = 0; r < 4; ++r) {
        const int row = row0 + r;
        float v = acc[mt][nt][r];
        if constexpr (MODE == 0) {
          v += bias[col];
          if (col < 1024) v *= 0.03125f;
          ((u16*)C)[(size_t)b * bsC + (size_t)row * ldc + col] = f2bf(v);
        } else {
          const int cl = wc * 64 + nt * 16 + m_l;
          const int rl2 = wr * 128 + mt * 16 + q * 4 + r;
          const u32 wb = ((const u32*)&sm[0][0][0])[rl2 * 8 + (cl >> 5)];
          v = ((wb >> (cl & 31)) & 1u) ? __expf(fminf(v, 30.f)) : 0.f;
          ((u16*)C)[(size_t)b * bsC + (size_t)row * ldc + col] = f2bf(v);
        }
      }
    }
  }
}

// ----- legacy 128-tile GEMM core (kept for MODE 2 / MODE 3 steps) -----
// MODE 2: ones-MFMA rowsum, v/rowsum+bias, fp32 | MODE 3: transposed bf16 store
template <int MODE, int TM, int BN>
__device__ __forceinline__ void gemm_core(
    u16* As, u16* Bs,
    const u16* __restrict__ A, long lda, long bsA,
    const u16* __restrict__ Bt, long ldb, long bsB,
    void* __restrict__ C, long ldc, long bsC,
    int M, int N, int K,
    const float* __restrict__ bias, const u32* __restrict__ mbits,
    int b, int bx, int by) {
  constexpr int MT = TM / 32, NT = BN / 32;
  constexpr int ACALLS = TM / 8, TOT = (TM + BN) / 8, NC = TOT / 4;
  const int m0 = by * TM, n0 = bx * BN;
  const int lane = threadIdx.x & 63;
  const int w = threadIdx.x >> 6;
  const int wr = w >> 1, wc = w & 1;

  const int srow = lane >> 3;
  const int scol = ((lane & 7) ^ ((lane >> 3) & 7)) * 8;
  const u16* pa = A + (size_t)b * bsA + (size_t)(m0 + srow) * lda + scol;
  const u16* pb = Bt + (size_t)b * bsB + (size_t)(n0 + srow) * ldb + scol;

  const int m_l = lane & 15, q = lane >> 4, m7 = m_l & 7;
  const int offs[2] = {(q ^ m7) * 8, ((4 + q) ^ m7) * 8};

  f32x4 acc[MT][NT] = {};
  f32x4 accs[MT] = {};
  bf16x8 ones;
#pragma unroll
  for (int e = 0; e < 8; ++e) ones[e] = (__bf16)1.0f;

  for (int kt = 0; kt < K; kt += 64) {
    __syncthreads();
#pragma unroll
    for (int g = 0; g < NC; ++g) {
      const int idx = w * NC + g;
      if (idx < ACALLS)
        async16(pa + (size_t)(idx * 8) * lda, As + idx * 512);
      else
        async16(pb + (size_t)((idx - ACALLS) * 8) * ldb, Bs + (idx - ACALLS) * 512);
    }
    __syncthreads();
#pragma unroll
    for (int s = 0; s < 2; ++s) {
      bf16x8 af[MT], bfr[NT];
#pragma unroll
      for (int t = 0; t < MT; ++t)
        af[t] = *(const bf16x8*)(As + (wr * (TM / 2) + t * 16 + m_l) * 64 + offs[s]);
#pragma unroll
      for (int t = 0; t < NT; ++t)
        bfr[t] = *(const bf16x8*)(Bs + (wc * (BN / 2) + t * 16 + m_l) * 64 + offs[s]);
#pragma unroll
      for (int mt = 0; mt < MT; ++mt)
#pragma unroll
        for (int nt = 0; nt < NT; ++nt)
          acc[mt][nt] = __builtin_amdgcn_mfma_f32_16x16x32_bf16(af[mt], bfr[nt], acc[mt][nt], 0, 0, 0);
      if constexpr (MODE == 2) {
#pragma unroll
        for (int mt = 0; mt < MT; ++mt)
          accs[mt] = __builtin_amdgcn_mfma_f32_16x16x32_bf16(af[mt], ones, accs[mt], 0, 0, 0);
      }
    }
    pa += 64;
    pb += 64;
  }

  float rinv[MT][4];
  if constexpr (MODE == 2) {
#pragma unroll
    for (int mt = 0; mt < MT; ++mt)
#pragma unroll
      for (int r = 0; r < 4; ++r) rinv[mt][r] = 1.0f / accs[mt][r];
  }

#pragma unroll
  for (int mt = 0; mt < MT; ++mt) {
#pragma unroll
    for (int nt = 0; nt < NT; ++nt) {
      const int col = n0 + wc * (BN / 2) + nt * 16 + m_l;
      const int row0 = m0 + wr * (TM / 2) + mt * 16 + q * 4;
      if constexpr (MODE == 3) {
        ushort4 o;
        o.x = f2bf(acc[mt][nt][0]); o.y = f2bf(acc[mt][nt][1]);
        o.z = f2bf(acc[mt][nt][2]); o.w = f2bf(acc[mt][nt][3]);
        *(ushort4*)((u16*)C + (size_t)b * bsC + (size_t)col * ldc + row0) = o;
      } else {
#pragma unroll
        for (int r = 0; r < 4; ++r) {
          const int row = row0 + r;
          float v = acc[mt][nt][r];
          if constexpr (MODE == 2) {
            v = v * rinv[mt][r] + bias[col];
            ((float*)C)[(size_t)b * bsC + (size_t)row * ldc + col] = v;
          }
        }
      }
    }
  }
}

template <int MODE, int TM, int BN>
__global__ __launch_bounds__(256) void gemm_bt(
    const u16* __restrict__ A, long lda, long bsA,
    const u16* __restrict__ Bt, long ldb, long bsB,
    void* __restrict__ C, long ldc, long bsC,
    int M, int N, int K,
    const float* __restrict__ bias, const u32* __restrict__ mbits) {
  __shared__ u16 As[TM * 64];
  __shared__ u16 Bs[BN * 64];
  const int gx = gridDim.x, gxy = gridDim.x * gridDim.y;
  const int T = gxy * gridDim.z;
  int L = blockIdx.x + gx * blockIdx.y + gxy * blockIdx.z;
  L = (L & 7) * (T >> 3) + (L >> 3);  // T divisible by 8 for all our grids
  const int bz = L / gxy, r = L % gxy;
  gemm_core<MODE, TM, BN>(As, Bs, A, lda, bsA, Bt, ldb, bsB, C, ldc, bsC, M, N, K,
                          bias, mbits, bz, r % gx, r / gx);
}

extern "C" void kernel_launch(void* const* d_in, const int* in_sizes, int n_in,
                              void* d_out, int out_size, void* d_ws, size_t ws_size,
                              hipStream_t stream) {
  const float* x = (const float*)d_in[0];
  const int* mask = (const int*)d_in[1];
  const float* proj_w = (const float*)d_in[2];
  const float* proj_b = (const float*)d_in[3];
  const float* out_w = (const float*)d_in[4];
  const float* out_b = (const float*)d_in[5];
  float* out = (float*)d_out;

  char* ws = (char*)d_ws;
  u16* xb = (u16*)(ws);                      // 16.8 MB; Ut aliases after qkv
  u16* wt = (u16*)(ws + 16777216);           // 6.3 MB
  u16* owt = (u16*)(ws + 23068672);          // 2.1 MB
  u16* qkv = (u16*)(ws + 25165824);          // 50.3 MB
  u16* P = (u16*)(ws + 75497472);            // 33.6 MB
  u32* mbits = (u32*)(ws + 109051904);       // 2.1 MB
  u16* Ut = (u16*)xb;                        // 16.8 MB [4][1024][2048]

  // 1. prep
  k_prep<<<14336, 256, 0, stream>>>(x, xb, proj_w, wt, out_w, owt, mask, mbits);
  // 2. qkv = x @ proj_w + b (q prescaled 1/32)   T=384 (256^2 pipelined core)
  gemm256<0><<<dim3(12, 32, 1), 512, 0, stream>>>(
      xb, 1024, 0, wt, 1024, 0, qkv, 3072, 0, 8192, 3072, 1024, proj_b, nullptr);
  // 3. P = mask ? exp(q k^T / 32) : 0            T=256 (256^2 pipelined core)
  gemm256<1><<<dim3(8, 8, 4), 512, 0, stream>>>(
      qkv, 3072, (long)2048 * 3072, qkv + 1024, 3072, (long)2048 * 3072,
      P, 2048, (long)2048 * 2048, 2048, 2048, 1024, nullptr, mbits);
  // 4. Ut = (V @ out_w)^T                        T=1024
  gemm_bt<3, 64, 128><<<dim3(8, 32, 4), 256, 0, stream>>>(
      qkv + 2048, 3072, (long)2048 * 3072, owt, 1024, 0,
      Ut, 2048, (long)1024 * 2048, 2048, 1024, 1024, nullptr, nullptr);
  // 5. out = P @ U / rowsum(P) + out_b           T=512
  gemm_bt<2, 128, 128><<<dim3(8, 16, 4), 256, 0, stream>>>(
      P, 2048, (long)2048 * 2048, Ut, 2048, (long)1024 * 2048,
      out, 1024, (long)2048 * 1024, 2048, 1024, 2048, out_b, nullptr);
}

// Round 6
// 317.920 us; speedup vs baseline: 1.0197x; 1.0197x over previous
//
#include <hip/hip_runtime.h>
#include <cstdint>

typedef unsigned short u16;
typedef uint32_t u32;
typedef __bf16 bf16x8 __attribute__((ext_vector_type(8)));
typedef float f32x4 __attribute__((ext_vector_type(4)));

__device__ __forceinline__ u16 f2bf(float f) {
  unsigned u = __float_as_uint(f);
  u += 0x7fffu + ((u >> 16) & 1u);
  return (u16)(u >> 16);
}

__device__ __forceinline__ void async16(const void* g, void* l) {
  __builtin_amdgcn_global_load_lds(
      (const __attribute__((address_space(1))) uint32_t*)g,
      (__attribute__((address_space(3))) uint32_t*)l, 16, 0, 0);
}

// --- fused prep: x->bf16 | proj_w^T | out_w^T | mask bitpack (one dispatch) ---
__global__ __launch_bounds__(256) void k_prep(const float* __restrict__ x, u16* __restrict__ xb,
                                              const float* __restrict__ pw, u16* __restrict__ wt,
                                              const float* __restrict__ ow, u16* __restrict__ owt,
                                              const int* __restrict__ mask, u32* __restrict__ mbits) {
  const int bid = blockIdx.x;
  if (bid < 8192) {
    const int i = bid * 256 + threadIdx.x;
    const float4 v = ((const float4*)x)[i];
    ushort4 o;
    o.x = f2bf(v.x); o.y = f2bf(v.y); o.z = f2bf(v.z); o.w = f2bf(v.w);
    ((ushort4*)xb)[i] = o;
    return;
  }
  if (bid >= 12288) {
    const size_t w = (size_t)(bid - 12288) * 256 + threadIdx.x;
    const int* p = mask + w * 32;
    u32 bits = 0;
#pragma unroll
    for (int j = 0; j < 8; ++j) {
      const int4 v = ((const int4*)p)[j];
      bits |= (u32)(v.x & 1) << (j * 4 + 0);
      bits |= (u32)(v.y & 1) << (j * 4 + 1);
      bits |= (u32)(v.z & 1) << (j * 4 + 2);
      bits |= (u32)(v.w & 1) << (j * 4 + 3);
    }
    mbits[w] = bits;
    return;
  }
  __shared__ u16 tile[32][33];
  const int tx = threadIdx.x & 31, ty = threadIdx.x >> 5;
  const float* in;
  u16* outp;
  int lda, ldo, c0, r0;
  if (bid < 11264) {
    const int id = bid - 8192;  // proj_w [1024][3072] -> wt [3072][1024]
    c0 = (id % 96) * 32; r0 = (id / 96) * 32;
    in = pw; outp = wt; lda = 3072; ldo = 1024;
  } else {
    const int id = bid - 11264;  // out_w [1024][1024] -> owt
    c0 = (id % 32) * 32; r0 = (id / 32) * 32;
    in = ow; outp = owt; lda = 1024; ldo = 1024;
  }
#pragma unroll
  for (int i = 0; i < 4; ++i)
    tile[ty + i * 8][tx] = f2bf(in[(size_t)(r0 + ty + i * 8) * lda + c0 + tx]);
  __syncthreads();
#pragma unroll
  for (int i = 0; i < 4; ++i)
    outp[(size_t)(c0 + ty + i * 8) * ldo + r0 + tx] = tile[tx][ty + i * 8];
}

// =====================================================================
// 256x128-tile CO-RESIDENT pipelined core: 512 thr = 8 waves (4x2),
// wave-tile 64x64 (acc = 64 VGPR), 3 LDS buffers x 24 KiB = 72 KiB
// -> 2 blocks/CU (the m97/m114 mechanism: the other block's waves cover
// the lgkm0/vmcnt drains that r2-r5 proved un-hideable intra-block).
// Depth-2 global prefetch, end-of-window vmcnt(3) (never 0 mid-loop).
// launch_bounds(512,4): 4 waves/SIMD => 128 VGPR cap (acc 64 + frags 32 fit).
// LDS layout per buf: A = 128 lines x 128B (256 rows), B = 64 lines (128
// rows); line l = rows {2l,2l+1}; group gg = go^(l&7), go=(row&1)*4+k16
// -> conflict-free (0 measured, r2). global_load_lds dest LINEAR; source
// carries the inverse permutation (both-sides-or-neither).
// MODE 0: +bias[col], cols<1024 *1/32, bf16 | MODE 1: mask+exp, bf16
// =====================================================================
template <int MODE>
__global__ __launch_bounds__(512, 4) void gemm256(
    const u16* __restrict__ A, long lda, long bsA,
    const u16* __restrict__ Bt, long ldb, long bsB,
    void* __restrict__ C, long ldc, long bsC,
    int M, int N, int K,
    const float* __restrict__ bias, const u32* __restrict__ mbits) {
  __shared__ u16 sm[3][12288];  // [buf][A:8192 | B:4096] u16 = 72 KiB
  const int gx = gridDim.x, gxy = gridDim.x * gridDim.y;
  const int T = gxy * gridDim.z;
  int L = blockIdx.x + gx * blockIdx.y + gxy * blockIdx.z;
  L = (L & 7) * (T >> 3) + (L >> 3);  // XCD swizzle; T divisible by 8
  const int b = L / gxy, rr = L % gxy, bx = rr % gx, by = rr / gx;
  const int m0 = by * 256, n0 = bx * 128;
  const int tid = threadIdx.x;
  const int lane = tid & 63;
  const int w = tid >> 6;
  const int wr = w >> 1, wc = w & 1;  // 4 x 2 waves, wave tile 64x64

  // ---- staging: A slots tid (rows 0..127) / tid+512 (rows 128..255),
  // B slots tid (rows 0..127). slot s: line l=s>>3, gg=s&7, go=gg^(l&7),
  // row = 2l + (go>>2), k-offset = (go&3)*8 u16.
  const int sl = tid >> 3;
  const int sgo = (tid & 7) ^ (sl & 7);
  const int srow = 2 * sl + (sgo >> 2);
  const int skoff = (sgo & 3) * 8;
  const u16* pa = A + (size_t)b * bsA + (size_t)(m0 + srow) * lda + skoff;
  const u16* pb = Bt + (size_t)b * bsB + (size_t)(n0 + srow) * ldb + skoff;
  const size_t a128 = (size_t)128 * lda;

  // ---- fragment read bases (u16): row r, k16=q -> line r>>1,
  // g = ((r&1)*4 + q) ^ ((r>>1)&7), addr = line*64 + g*8.
  const int m_l = lane & 15, q = lane >> 4;
  const int l7 = m_l >> 1;  // (r>>1)&7; mt stride = 16 rows = 8 lines
  const int g = (((m_l & 1) * 4) + q) ^ l7;
  const int aoff = wr * 2048 + l7 * 64 + g * 8;      // wr*64 rows = wr*32 lines
  const int boff = 8192 + wc * 2048 + l7 * 64 + g * 8;  // wc*64 rows

  f32x4 acc[4][4] = {};

#define MFMA_(A_, B_, C_) __builtin_amdgcn_mfma_f32_16x16x32_bf16(A_, B_, C_, 0, 0, 0)
#define STAGE(tt, bi)                               \
  {                                                 \
    const size_t ko_ = (size_t)(tt)*32;             \
    u16* da_ = &sm[bi][0] + tid * 8;                \
    async16(pa + ko_, da_);                         \
    async16(pa + ko_ + a128, da_ + 4096);           \
    async16(pb + ko_, &sm[bi][8192] + tid * 8);     \
  }

  const int NTL = K >> 5;  // K-tiles of 32
  STAGE(0, 0) STAGE(1, 1)
  asm volatile("s_waitcnt vmcnt(3)" ::: "memory");  // tile 0 landed
  __builtin_amdgcn_s_barrier();

  int br = 0, bs = 2;  // read buf = t%3, stage buf = (t+2)%3
  for (int t = 0; t < NTL; ++t) {
    if (t + 2 < NTL) STAGE(t + 2, bs)
    const u16* ab = &sm[br][0] + aoff;
    const u16* bb = &sm[br][0] + boff;
    bf16x8 af[4], bf[4];
#pragma unroll
    for (int mt = 0; mt < 4; ++mt) af[mt] = *(const bf16x8*)(ab + mt * 512);
#pragma unroll
    for (int nt = 0; nt < 4; ++nt) bf[nt] = *(const bf16x8*)(bb + nt * 512);
    asm volatile("s_waitcnt lgkmcnt(0)" ::: "memory");
    __builtin_amdgcn_sched_barrier(0);
    __builtin_amdgcn_s_setprio(1);
#pragma unroll
    for (int mt = 0; mt < 4; ++mt)
#pragma unroll
      for (int nt = 0; nt < 4; ++nt)
        acc[mt][nt] = MFMA_(af[mt], bf[nt], acc[mt][nt]);
    __builtin_amdgcn_s_setprio(0);
    __builtin_amdgcn_sched_barrier(0);
    if (t + 2 < NTL) {
      asm volatile("s_waitcnt vmcnt(3)" ::: "memory");  // tile t+1 landed
    } else if (t + 1 < NTL) {
      asm volatile("s_waitcnt vmcnt(0)" ::: "memory");
    }
    if (t + 1 < NTL) __builtin_amdgcn_s_barrier();
    br = (br == 2) ? 0 : br + 1;
    bs = (bs == 2) ? 0 : bs + 1;
  }
#undef STAGE
#undef MFMA_

  if constexpr (MODE == 1) {
    __syncthreads();
    // mask bits for this tile: 256 rows x 4 words (128 cols)
    u32* smw = (u32*)&sm[0][0];
    const int rl = tid >> 1, pr = tid & 1;
    const uint2 mv = *(const uint2*)(mbits + ((size_t)b * M + m0 + rl) * (N >> 5) + (n0 >> 5) + pr * 2);
    smw[rl * 4 + pr * 2] = mv.x;
    smw[rl * 4 + pr * 2 + 1] = mv.y;
    __syncthreads();
  }

#pragma unroll
  for (int mt = 0; mt < 4; ++mt) {
#pragma unroll
    for (int nt = 0; nt < 4; ++nt) {
      const int col = n0 + wc * 64 + nt * 16 + m_l;
      const int row0 = m0 + wr * 64 + mt * 16 + q * 4;
#pragma unroll
      for (int r = 0; r < 4; ++r) {
        const int row = row0 + r;
        float v = acc[mt][nt][r];
        if constexpr (MODE == 0) {
          v += bias[col];
          if (col < 1024) v *= 0.03125f;
          ((u16*)C)[(size_t)b * bsC + (size_t)row * ldc + col] = f2bf(v);
        } else {
          const int cl = wc * 64 + nt * 16 + m_l;
          const int rl2 = wr * 64 + mt * 16 + q * 4 + r;
          const u32 wb = ((const u32*)&sm[0][0])[rl2 * 4 + (cl >> 5)];
          v = ((wb >> (cl & 31)) & 1u) ? __expf(fminf(v, 30.f)) : 0.f;
          ((u16*)C)[(size_t)b * bsC + (size_t)row * ldc + col] = f2bf(v);
        }
      }
    }
  }
}

// ----- legacy 128-tile GEMM core (kept for MODE 2 / MODE 3 steps) -----
// MODE 2: ones-MFMA rowsum, v/rowsum+bias, fp32 | MODE 3: transposed bf16 store
template <int MODE, int TM, int BN>
__device__ __forceinline__ void gemm_core(
    u16* As, u16* Bs,
    const u16* __restrict__ A, long lda, long bsA,
    const u16* __restrict__ Bt, long ldb, long bsB,
    void* __restrict__ C, long ldc, long bsC,
    int M, int N, int K,
    const float* __restrict__ bias, const u32* __restrict__ mbits,
    int b, int bx, int by) {
  constexpr int MT = TM / 32, NT = BN / 32;
  constexpr int ACALLS = TM / 8, TOT = (TM + BN) / 8, NC = TOT / 4;
  const int m0 = by * TM, n0 = bx * BN;
  const int lane = threadIdx.x & 63;
  const int w = threadIdx.x >> 6;
  const int wr = w >> 1, wc = w & 1;

  const int srow = lane >> 3;
  const int scol = ((lane & 7) ^ ((lane >> 3) & 7)) * 8;
  const u16* pa = A + (size_t)b * bsA + (size_t)(m0 + srow) * lda + scol;
  const u16* pb = Bt + (size_t)b * bsB + (size_t)(n0 + srow) * ldb + scol;

  const int m_l = lane & 15, q = lane >> 4, m7 = m_l & 7;
  const int offs[2] = {(q ^ m7) * 8, ((4 + q) ^ m7) * 8};

  f32x4 acc[MT][NT] = {};
  f32x4 accs[MT] = {};
  bf16x8 ones;
#pragma unroll
  for (int e = 0; e < 8; ++e) ones[e] = (__bf16)1.0f;

  for (int kt = 0; kt < K; kt += 64) {
    __syncthreads();
#pragma unroll
    for (int g = 0; g < NC; ++g) {
      const int idx = w * NC + g;
      if (idx < ACALLS)
        async16(pa + (size_t)(idx * 8) * lda, As + idx * 512);
      else
        async16(pb + (size_t)((idx - ACALLS) * 8) * ldb, Bs + (idx - ACALLS) * 512);
    }
    __syncthreads();
#pragma unroll
    for (int s = 0; s < 2; ++s) {
      bf16x8 af[MT], bfr[NT];
#pragma unroll
      for (int t = 0; t < MT; ++t)
        af[t] = *(const bf16x8*)(As + (wr * (TM / 2) + t * 16 + m_l) * 64 + offs[s]);
#pragma unroll
      for (int t = 0; t < NT; ++t)
        bfr[t] = *(const bf16x8*)(Bs + (wc * (BN / 2) + t * 16 + m_l) * 64 + offs[s]);
#pragma unroll
      for (int mt = 0; mt < MT; ++mt)
#pragma unroll
        for (int nt = 0; nt < NT; ++nt)
          acc[mt][nt] = __builtin_amdgcn_mfma_f32_16x16x32_bf16(af[mt], bfr[nt], acc[mt][nt], 0, 0, 0);
      if constexpr (MODE == 2) {
#pragma unroll
        for (int mt = 0; mt < MT; ++mt)
          accs[mt] = __builtin_amdgcn_mfma_f32_16x16x32_bf16(af[mt], ones, accs[mt], 0, 0, 0);
      }
    }
    pa += 64;
    pb += 64;
  }

  float rinv[MT][4];
  if constexpr (MODE == 2) {
#pragma unroll
    for (int mt = 0; mt < MT; ++mt)
#pragma unroll
      for (int r = 0; r < 4; ++r) rinv[mt][r] = 1.0f / accs[mt][r];
  }

#pragma unroll
  for (int mt = 0; mt < MT; ++mt) {
#pragma unroll
    for (int nt = 0; nt < NT; ++nt) {
      const int col = n0 + wc * (BN / 2) + nt * 16 + m_l;
      const int row0 = m0 + wr * (TM / 2) + mt * 16 + q * 4;
      if constexpr (MODE == 3) {
        ushort4 o;
        o.x = f2bf(acc[mt][nt][0]); o.y = f2bf(acc[mt][nt][1]);
        o.z = f2bf(acc[mt][nt][2]); o.w = f2bf(acc[mt][nt][3]);
        *(ushort4*)((u16*)C + (size_t)b * bsC + (size_t)col * ldc + row0) = o;
      } else {
#pragma unroll
        for (int r = 0; r < 4; ++r) {
          const int row = row0 + r;
          float v = acc[mt][nt][r];
          if constexpr (MODE == 2) {
            v = v * rinv[mt][r] + bias[col];
            ((float*)C)[(size_t)b * bsC + (size_t)row * ldc + col] = v;
          }
        }
      }
    }
  }
}

template <int MODE, int TM, int BN>
__global__ __launch_bounds__(256) void gemm_bt(
    const u16* __restrict__ A, long lda, long bsA,
    const u16* __restrict__ Bt, long ldb, long bsB,
    void* __restrict__ C, long ldc, long bsC,
    int M, int N, int K,
    const float* __restrict__ bias, const u32* __restrict__ mbits) {
  __shared__ u16 As[TM * 64];
  __shared__ u16 Bs[BN * 64];
  const int gx = gridDim.x, gxy = gridDim.x * gridDim.y;
  const int T = gxy * gridDim.z;
  int L = blockIdx.x + gx * blockIdx.y + gxy * blockIdx.z;
  L = (L & 7) * (T >> 3) + (L >> 3);  // T divisible by 8 for all our grids
  const int bz = L / gxy, r = L % gxy;
  gemm_core<MODE, TM, BN>(As, Bs, A, lda, bsA, Bt, ldb, bsB, C, ldc, bsC, M, N, K,
                          bias, mbits, bz, r % gx, r / gx);
}

extern "C" void kernel_launch(void* const* d_in, const int* in_sizes, int n_in,
                              void* d_out, int out_size, void* d_ws, size_t ws_size,
                              hipStream_t stream) {
  const float* x = (const float*)d_in[0];
  const int* mask = (const int*)d_in[1];
  const float* proj_w = (const float*)d_in[2];
  const float* proj_b = (const float*)d_in[3];
  const float* out_w = (const float*)d_in[4];
  const float* out_b = (const float*)d_in[5];
  float* out = (float*)d_out;

  char* ws = (char*)d_ws;
  u16* xb = (u16*)(ws);                      // 16.8 MB; Ut aliases after qkv
  u16* wt = (u16*)(ws + 16777216);           // 6.3 MB
  u16* owt = (u16*)(ws + 23068672);          // 2.1 MB
  u16* qkv = (u16*)(ws + 25165824);          // 50.3 MB
  u16* P = (u16*)(ws + 75497472);            // 33.6 MB
  u32* mbits = (u32*)(ws + 109051904);       // 2.1 MB
  u16* Ut = (u16*)xb;                        // 16.8 MB [4][1024][2048]

  // 1. prep
  k_prep<<<14336, 256, 0, stream>>>(x, xb, proj_w, wt, out_w, owt, mask, mbits);
  // 2. qkv = x @ proj_w + b (q prescaled 1/32)   T=768 (256x128, 2 blk/CU)
  gemm256<0><<<dim3(24, 32, 1), 512, 0, stream>>>(
      xb, 1024, 0, wt, 1024, 0, qkv, 3072, 0, 8192, 3072, 1024, proj_b, nullptr);
  // 3. P = mask ? exp(q k^T / 32) : 0            T=512 (256x128, 2 blk/CU)
  gemm256<1><<<dim3(16, 8, 4), 512, 0, stream>>>(
      qkv, 3072, (long)2048 * 3072, qkv + 1024, 3072, (long)2048 * 3072,
      P, 2048, (long)2048 * 2048, 2048, 2048, 1024, nullptr, mbits);
  // 4. Ut = (V @ out_w)^T                        T=1024
  gemm_bt<3, 64, 128><<<dim3(8, 32, 4), 256, 0, stream>>>(
      qkv + 2048, 3072, (long)2048 * 3072, owt, 1024, 0,
      Ut, 2048, (long)1024 * 2048, 2048, 1024, 1024, nullptr, nullptr);
  // 5. out = P @ U / rowsum(P) + out_b           T=512
  gemm_bt<2, 128, 128><<<dim3(8, 16, 4), 256, 0, stream>>>(
      P, 2048, (long)2048 * 2048, Ut, 2048, (long)1024 * 2048,
      out, 1024, (long)2048 * 1024, 2048, 1024, 2048, out_b, nullptr);
}

// Round 8
// 316.497 us; speedup vs baseline: 1.0243x; 1.0045x over previous
//
#include <hip/hip_runtime.h>
#include <cstdint>

typedef unsigned short u16;
typedef uint32_t u32;
typedef __bf16 bf16x8 __attribute__((ext_vector_type(8)));
typedef float f32x4 __attribute__((ext_vector_type(4)));

__device__ __forceinline__ u16 f2bf(float f) {
  unsigned u = __float_as_uint(f);
  u += 0x7fffu + ((u >> 16) & 1u);
  return (u16)(u >> 16);
}

__device__ __forceinline__ void async16(const void* g, void* l) {
  __builtin_amdgcn_global_load_lds(
      (const __attribute__((address_space(1))) uint32_t*)g,
      (__attribute__((address_space(3))) uint32_t*)l, 16, 0, 0);
}

// --- fused prep: x->bf16 | proj_w^T | out_w^T | mask bitpack (one dispatch) ---
__global__ __launch_bounds__(256) void k_prep(const float* __restrict__ x, u16* __restrict__ xb,
                                              const float* __restrict__ pw, u16* __restrict__ wt,
                                              const float* __restrict__ ow, u16* __restrict__ owt,
                                              const int* __restrict__ mask, u32* __restrict__ mbits) {
  const int bid = blockIdx.x;
  if (bid < 8192) {
    const int i = bid * 256 + threadIdx.x;
    const float4 v = ((const float4*)x)[i];
    ushort4 o;
    o.x = f2bf(v.x); o.y = f2bf(v.y); o.z = f2bf(v.z); o.w = f2bf(v.w);
    ((ushort4*)xb)[i] = o;
    return;
  }
  if (bid >= 12288) {
    const size_t w = (size_t)(bid - 12288) * 256 + threadIdx.x;
    const int* p = mask + w * 32;
    u32 bits = 0;
#pragma unroll
    for (int j = 0; j < 8; ++j) {
      const int4 v = ((const int4*)p)[j];
      bits |= (u32)(v.x & 1) << (j * 4 + 0);
      bits |= (u32)(v.y & 1) << (j * 4 + 1);
      bits |= (u32)(v.z & 1) << (j * 4 + 2);
      bits |= (u32)(v.w & 1) << (j * 4 + 3);
    }
    mbits[w] = bits;
    return;
  }
  __shared__ u16 tile[32][33];
  const int tx = threadIdx.x & 31, ty = threadIdx.x >> 5;
  const float* in;
  u16* outp;
  int lda, ldo, c0, r0;
  if (bid < 11264) {
    const int id = bid - 8192;  // proj_w [1024][3072] -> wt [3072][1024]
    c0 = (id % 96) * 32; r0 = (id / 96) * 32;
    in = pw; outp = wt; lda = 3072; ldo = 1024;
  } else {
    const int id = bid - 11264;  // out_w [1024][1024] -> owt
    c0 = (id % 32) * 32; r0 = (id / 32) * 32;
    in = ow; outp = owt; lda = 1024; ldo = 1024;
  }
#pragma unroll
  for (int i = 0; i < 4; ++i)
    tile[ty + i * 8][tx] = f2bf(in[(size_t)(r0 + ty + i * 8) * lda + c0 + tx]);
  __syncthreads();
#pragma unroll
  for (int i = 0; i < 4; ++i)
    outp[(size_t)(c0 + ty + i * 8) * ldo + r0 + tx] = tile[tx][ty + i * 8];
}

// =====================================================================
// 256x128-tile CO-RESIDENT pipelined core (r6 structure, r8 wait fix):
// 512 thr = 8 waves (4x2), wave-tile 64x64, 3 LDS bufs x 24 KiB = 72 KiB
// -> 2 blocks/CU. Depth-2 prefetch, end-of-window vmcnt(3), never 0 mid-loop.
// r8 (vs r6): NO manual lgkmcnt(0)/sched_barrier -- compiler emits
// staggered lgkmcnt(N) per MFMA first-use (m97-verified), overlapping the
// 8-read drain with the MFMA cluster. Barriers are asm s_barrier with a
// "memory" clobber: required so next-window ds_reads can't hoist above
// the barrier (builtin s_barrier is not a compiler memory fence).
// WAR audit: wave-own reads complete before their MFMAs (compiler waits),
// all MFMAs precede the barrier, so buf t%3 reads are done in all waves
// before any wave issues STAGE(t+3) into that buf after the barrier.
// r7 lesson (NaN): global_load_lds imm offset applies to BOTH global and
// LDS addresses -- do NOT use it to walk K-tiles; advance pointers instead.
// LDS layout: line l = rows {2l,2l+1}; group gg = go^(l&7), go=(row&1)*4+k16
// -> conflict-free (0 measured r2/r6). DMA dest LINEAR; source pre-permuted.
// MODE 0: +bias[col], cols<1024 *1/32, bf16 | MODE 1: mask+exp, bf16
// =====================================================================
template <int MODE>
__global__ __launch_bounds__(512, 4) void gemm256(
    const u16* __restrict__ A, long lda, long bsA,
    const u16* __restrict__ Bt, long ldb, long bsB,
    void* __restrict__ C, long ldc, long bsC,
    int M, int N, int K,
    const float* __restrict__ bias, const u32* __restrict__ mbits) {
  __shared__ u16 sm[3][12288];  // [buf][A:8192 | B:4096] u16 = 72 KiB
  const int gx = gridDim.x, gxy = gridDim.x * gridDim.y;
  const int T = gxy * gridDim.z;
  int L = blockIdx.x + gx * blockIdx.y + gxy * blockIdx.z;
  L = (L & 7) * (T >> 3) + (L >> 3);  // XCD swizzle; T divisible by 8
  const int b = L / gxy, rr = L % gxy, bx = rr % gx, by = rr / gx;
  const int m0 = by * 256, n0 = bx * 128;
  const int tid = threadIdx.x;
  const int lane = tid & 63;
  const int w = tid >> 6;
  const int wr = w >> 1, wc = w & 1;  // 4 x 2 waves, wave tile 64x64

  // ---- staging: A slots tid (rows 0..127) / tid+512 (rows 128..255),
  // B slots tid (rows 0..127). slot s: line l=s>>3, gg=s&7, go=gg^(l&7),
  // row = 2l + (go>>2), k-offset = (go&3)*8 u16.
  const int sl = tid >> 3;
  const int sgo = (tid & 7) ^ (sl & 7);
  const int srow = 2 * sl + (sgo >> 2);
  const int skoff = (sgo & 3) * 8;
  const u16* pa = A + (size_t)b * bsA + (size_t)(m0 + srow) * lda + skoff;
  const u16* pb = Bt + (size_t)b * bsB + (size_t)(n0 + srow) * ldb + skoff;
  const size_t a128 = (size_t)128 * lda;

  // ---- fragment read bases (u16): row r, k16=q -> line r>>1,
  // g = ((r&1)*4 + q) ^ ((r>>1)&7), addr = line*64 + g*8.
  const int m_l = lane & 15, q = lane >> 4;
  const int l7 = m_l >> 1;  // (r>>1)&7; mt stride = 16 rows = 8 lines
  const int g = (((m_l & 1) * 4) + q) ^ l7;
  const int aoff = wr * 2048 + l7 * 64 + g * 8;      // wr*64 rows = wr*32 lines
  const int boff = 8192 + wc * 2048 + l7 * 64 + g * 8;  // wc*64 rows

  f32x4 acc[4][4] = {};

#define MFMA_(A_, B_, C_) __builtin_amdgcn_mfma_f32_16x16x32_bf16(A_, B_, C_, 0, 0, 0)
#define STAGE(tt, bi)                               \
  {                                                 \
    const size_t ko_ = (size_t)(tt)*32;             \
    u16* da_ = &sm[bi][0] + tid * 8;                \
    async16(pa + ko_, da_);                         \
    async16(pa + ko_ + a128, da_ + 4096);           \
    async16(pb + ko_, &sm[bi][8192] + tid * 8);     \
  }

  const int NTL = K >> 5;  // K-tiles of 32
  STAGE(0, 0) STAGE(1, 1)
  asm volatile("s_waitcnt vmcnt(3)" ::: "memory");  // tile 0 landed
  asm volatile("s_barrier" ::: "memory");

  int br = 0, bs = 2;  // read buf = t%3, stage buf = (t+2)%3
  for (int t = 0; t < NTL; ++t) {
    if (t + 2 < NTL) STAGE(t + 2, bs)
    const u16* ab = &sm[br][0] + aoff;
    const u16* bb = &sm[br][0] + boff;
    bf16x8 af[4], bf[4];
#pragma unroll
    for (int mt = 0; mt < 4; ++mt) af[mt] = *(const bf16x8*)(ab + mt * 512);
#pragma unroll
    for (int nt = 0; nt < 4; ++nt) bf[nt] = *(const bf16x8*)(bb + nt * 512);
    __builtin_amdgcn_s_setprio(1);
#pragma unroll
    for (int mt = 0; mt < 4; ++mt)
#pragma unroll
      for (int nt = 0; nt < 4; ++nt)
        acc[mt][nt] = MFMA_(af[mt], bf[nt], acc[mt][nt]);
    __builtin_amdgcn_s_setprio(0);
    if (t + 2 < NTL) {
      asm volatile("s_waitcnt vmcnt(3)" ::: "memory");  // tile t+1 landed
    } else if (t + 1 < NTL) {
      asm volatile("s_waitcnt vmcnt(0)" ::: "memory");
    }
    if (t + 1 < NTL) asm volatile("s_barrier" ::: "memory");
    br = (br == 2) ? 0 : br + 1;
    bs = (bs == 2) ? 0 : bs + 1;
  }
#undef STAGE
#undef MFMA_

  if constexpr (MODE == 1) {
    __syncthreads();
    // mask bits for this tile: 256 rows x 4 words (128 cols)
    u32* smw = (u32*)&sm[0][0];
    const int rl = tid >> 1, pr = tid & 1;
    const uint2 mv = *(const uint2*)(mbits + ((size_t)b * M + m0 + rl) * (N >> 5) + (n0 >> 5) + pr * 2);
    smw[rl * 4 + pr * 2] = mv.x;
    smw[rl * 4 + pr * 2 + 1] = mv.y;
    __syncthreads();
  }

#pragma unroll
  for (int mt = 0; mt < 4; ++mt) {
#pragma unroll
    for (int nt = 0; nt < 4; ++nt) {
      const int col = n0 + wc * 64 + nt * 16 + m_l;
      const int row0 = m0 + wr * 64 + mt * 16 + q * 4;
#pragma unroll
      for (int r = 0; r < 4; ++r) {
        const int row = row0 + r;
        float v = acc[mt][nt][r];
        if constexpr (MODE == 0) {
          v += bias[col];
          if (col < 1024) v *= 0.03125f;
          ((u16*)C)[(size_t)b * bsC + (size_t)row * ldc + col] = f2bf(v);
        } else {
          const int cl = wc * 64 + nt * 16 + m_l;
          const int rl2 = wr * 64 + mt * 16 + q * 4 + r;
          const u32 wb = ((const u32*)&sm[0][0])[rl2 * 4 + (cl >> 5)];
          v = ((wb >> (cl & 31)) & 1u) ? __expf(fminf(v, 30.f)) : 0.f;
          ((u16*)C)[(size_t)b * bsC + (size_t)row * ldc + col] = f2bf(v);
        }
      }
    }
  }
}

// ----- legacy 128-tile GEMM core (kept for MODE 2 / MODE 3 steps) -----
// MODE 2: ones-MFMA rowsum, v/rowsum+bias, fp32 | MODE 3: transposed bf16 store
template <int MODE, int TM, int BN>
__device__ __forceinline__ void gemm_core(
    u16* As, u16* Bs,
    const u16* __restrict__ A, long lda, long bsA,
    const u16* __restrict__ Bt, long ldb, long bsB,
    void* __restrict__ C, long ldc, long bsC,
    int M, int N, int K,
    const float* __restrict__ bias, const u32* __restrict__ mbits,
    int b, int bx, int by) {
  constexpr int MT = TM / 32, NT = BN / 32;
  constexpr int ACALLS = TM / 8, TOT = (TM + BN) / 8, NC = TOT / 4;
  const int m0 = by * TM, n0 = bx * BN;
  const int lane = threadIdx.x & 63;
  const int w = threadIdx.x >> 6;
  const int wr = w >> 1, wc = w & 1;

  const int srow = lane >> 3;
  const int scol = ((lane & 7) ^ ((lane >> 3) & 7)) * 8;
  const u16* pa = A + (size_t)b * bsA + (size_t)(m0 + srow) * lda + scol;
  const u16* pb = Bt + (size_t)b * bsB + (size_t)(n0 + srow) * ldb + scol;

  const int m_l = lane & 15, q = lane >> 4, m7 = m_l & 7;
  const int offs[2] = {(q ^ m7) * 8, ((4 + q) ^ m7) * 8};

  f32x4 acc[MT][NT] = {};
  f32x4 accs[MT] = {};
  bf16x8 ones;
#pragma unroll
  for (int e = 0; e < 8; ++e) ones[e] = (__bf16)1.0f;

  for (int kt = 0; kt < K; kt += 64) {
    __syncthreads();
#pragma unroll
    for (int g = 0; g < NC; ++g) {
      const int idx = w * NC + g;
      if (idx < ACALLS)
        async16(pa + (size_t)(idx * 8) * lda, As + idx * 512);
      else
        async16(pb + (size_t)((idx - ACALLS) * 8) * ldb, Bs + (idx - ACALLS) * 512);
    }
    __syncthreads();
#pragma unroll
    for (int s = 0; s < 2; ++s) {
      bf16x8 af[MT], bfr[NT];
#pragma unroll
      for (int t = 0; t < MT; ++t)
        af[t] = *(const bf16x8*)(As + (wr * (TM / 2) + t * 16 + m_l) * 64 + offs[s]);
#pragma unroll
      for (int t = 0; t < NT; ++t)
        bfr[t] = *(const bf16x8*)(Bs + (wc * (BN / 2) + t * 16 + m_l) * 64 + offs[s]);
#pragma unroll
      for (int mt = 0; mt < MT; ++mt)
#pragma unroll
        for (int nt = 0; nt < NT; ++nt)
          acc[mt][nt] = __builtin_amdgcn_mfma_f32_16x16x32_bf16(af[mt], bfr[nt], acc[mt][nt], 0, 0, 0);
      if constexpr (MODE == 2) {
#pragma unroll
        for (int mt = 0; mt < MT; ++mt)
          accs[mt] = __builtin_amdgcn_mfma_f32_16x16x32_bf16(af[mt], ones, accs[mt], 0, 0, 0);
      }
    }
    pa += 64;
    pb += 64;
  }

  float rinv[MT][4];
  if constexpr (MODE == 2) {
#pragma unroll
    for (int mt = 0; mt < MT; ++mt)
#pragma unroll
      for (int r = 0; r < 4; ++r) rinv[mt][r] = 1.0f / accs[mt][r];
  }

#pragma unroll
  for (int mt = 0; mt < MT; ++mt) {
#pragma unroll
    for (int nt = 0; nt < NT; ++nt) {
      const int col = n0 + wc * (BN / 2) + nt * 16 + m_l;
      const int row0 = m0 + wr * (TM / 2) + mt * 16 + q * 4;
      if constexpr (MODE == 3) {
        ushort4 o;
        o.x = f2bf(acc[mt][nt][0]); o.y = f2bf(acc[mt][nt][1]);
        o.z = f2bf(acc[mt][nt][2]); o.w = f2bf(acc[mt][nt][3]);
        *(ushort4*)((u16*)C + (size_t)b * bsC + (size_t)col * ldc + row0) = o;
      } else {
#pragma unroll
        for (int r = 0; r < 4; ++r) {
          const int row = row0 + r;
          float v = acc[mt][nt][r];
          if constexpr (MODE == 2) {
            v = v * rinv[mt][r] + bias[col];
            ((float*)C)[(size_t)b * bsC + (size_t)row * ldc + col] = v;
          }
        }
      }
    }
  }
}

template <int MODE, int TM, int BN>
__global__ __launch_bounds__(256) void gemm_bt(
    const u16* __restrict__ A, long lda, long bsA,
    const u16* __restrict__ Bt, long ldb, long bsB,
    void* __restrict__ C, long ldc, long bsC,
    int M, int N, int K,
    const float* __restrict__ bias, const u32* __restrict__ mbits) {
  __shared__ u16 As[TM * 64];
  __shared__ u16 Bs[BN * 64];
  const int gx = gridDim.x, gxy = gridDim.x * gridDim.y;
  const int T = gxy * gridDim.z;
  int L = blockIdx.x + gx * blockIdx.y + gxy * blockIdx.z;
  L = (L & 7) * (T >> 3) + (L >> 3);  // T divisible by 8 for all our grids
  const int bz = L / gxy, r = L % gxy;
  gemm_core<MODE, TM, BN>(As, Bs, A, lda, bsA, Bt, ldb, bsB, C, ldc, bsC, M, N, K,
                          bias, mbits, bz, r % gx, r / gx);
}

extern "C" void kernel_launch(void* const* d_in, const int* in_sizes, int n_in,
                              void* d_out, int out_size, void* d_ws, size_t ws_size,
                              hipStream_t stream) {
  const float* x = (const float*)d_in[0];
  const int* mask = (const int*)d_in[1];
  const float* proj_w = (const float*)d_in[2];
  const float* proj_b = (const float*)d_in[3];
  const float* out_w = (const float*)d_in[4];
  const float* out_b = (const float*)d_in[5];
  float* out = (float*)d_out;

  char* ws = (char*)d_ws;
  u16* xb = (u16*)(ws);                      // 16.8 MB; Ut aliases after qkv
  u16* wt = (u16*)(ws + 16777216);           // 6.3 MB
  u16* owt = (u16*)(ws + 23068672);          // 2.1 MB
  u16* qkv = (u16*)(ws + 25165824);          // 50.3 MB
  u16* P = (u16*)(ws + 75497472);            // 33.6 MB
  u32* mbits = (u32*)(ws + 109051904);       // 2.1 MB
  u16* Ut = (u16*)xb;                        // 16.8 MB [4][1024][2048]

  // 1. prep
  k_prep<<<14336, 256, 0, stream>>>(x, xb, proj_w, wt, out_w, owt, mask, mbits);
  // 2. qkv = x @ proj_w + b (q prescaled 1/32)   T=768 (256x128, 2 blk/CU)
  gemm256<0><<<dim3(24, 32, 1), 512, 0, stream>>>(
      xb, 1024, 0, wt, 1024, 0, qkv, 3072, 0, 8192, 3072, 1024, proj_b, nullptr);
  // 3. P = mask ? exp(q k^T / 32) : 0            T=512 (256x128, 2 blk/CU)
  gemm256<1><<<dim3(16, 8, 4), 512, 0, stream>>>(
      qkv, 3072, (long)2048 * 3072, qkv + 1024, 3072, (long)2048 * 3072,
      P, 2048, (long)2048 * 2048, 2048, 2048, 1024, nullptr, mbits);
  // 4. Ut = (V @ out_w)^T                        T=1024
  gemm_bt<3, 64, 128><<<dim3(8, 32, 4), 256, 0, stream>>>(
      qkv + 2048, 3072, (long)2048 * 3072, owt, 1024, 0,
      Ut, 2048, (long)1024 * 2048, 2048, 1024, 1024, nullptr, nullptr);
  // 5. out = P @ U / rowsum(P) + out_b           T=512
  gemm_bt<2, 128, 128><<<dim3(8, 16, 4), 256, 0, stream>>>(
      P, 2048, (long)2048 * 2048, Ut, 2048, (long)1024 * 2048,
      out, 1024, (long)2048 * 1024, 2048, 1024, 2048, out_b, nullptr);
}